// Round 13
// baseline (134.725 us; speedup 1.0000x reference)
//
#include <hip/hip_runtime.h>
#include <math.h>

#define NN 4096
#define DD 256
#define EE 131072
#define MAXD 128
#define SP 132          // sS row stride; 132%32==4 -> conflict-free

typedef __attribute__((ext_vector_type(8))) short short8;
typedef __attribute__((ext_vector_type(4))) float float4v;

__device__ __forceinline__ unsigned short f2bf(float f){
    unsigned u = __float_as_uint(f);
    return (unsigned short)((u + 0x7fffu + ((u >> 16) & 1u)) >> 16);   // RNE
}
__device__ __forceinline__ float blo(unsigned u){ return __uint_as_float(u << 16); }
__device__ __forceinline__ float bhi(unsigned u){ return __uint_as_float(u & 0xffff0000u); }

// ---------------- K1: pack weights to MFMA fragments + zero adj ----------------
__device__ __forceinline__ void pack_one(const float* __restrict__ src, unsigned short* __restrict__ dst, int e){
    int lane = e & 63;
    int row = ((e >> 9) << 4) + (lane & 15);
    int k0 = ((e >> 6) & 7) * 32 + ((lane >> 4) << 3);
    const float* p = src + row * DD + k0;
    short8 v;
    #pragma unroll
    for (int j = 0; j < 8; ++j) v[j] = (short)f2bf(p[j]);
    ((short8*)dst)[e] = v;
}

__global__ void k_packw(const float* __restrict__ ipw, const float* __restrict__ ow, const float* __restrict__ lw,
                        unsigned short* __restrict__ bipw, unsigned short* __restrict__ bow,
                        unsigned short* __restrict__ blw, unsigned* __restrict__ adj){
    int e = blockIdx.x * 256 + threadIdx.x;       // 40960 threads
    for (int i = e; i < 524288; i += 40960) adj[i] = 0u;   // zero 2MB adj
    if (e < 24576)       pack_one(ipw, bipw, e);
    else if (e < 32768)  pack_one(ow,  bow,  e - 24576);
    else                 pack_one(lw,  blw,  e - 32768);
}

// ---------------- K2: QKV GEMM, 32 nodes/block (B-fragments reused 2x) + fused edge scatter ----
__global__ void __launch_bounds__(256) k_gqkv(const float* __restrict__ emb, const unsigned short* __restrict__ Bp,
                                              const float* __restrict__ bias, float* __restrict__ qf,
                                              unsigned short* __restrict__ kb, unsigned short* __restrict__ vb,
                                              const int* __restrict__ ei, unsigned* __restrict__ adj){
    __shared__ float sA[32 * 260];
    int bx = blockIdx.x, by = blockIdx.y;         // bx in [0,128)
    int t = threadIdx.x, w = t >> 6, lane = t & 63;

    // fire-and-forget edge scatter, grid-stride (384 blocks x 256 thr, stride 98304)
    for (int gid = (by * 128 + bx) * 256 + t; gid < EE; gid += 98304){
        int s = ei[gid], d = ei[EE + gid];
        if (s != d){
            atomicOr(&adj[s * 128 + (d >> 5)], 1u << (d & 31));
            atomicOr(&adj[d * 128 + (s >> 5)], 1u << (s & 31));
        }
    }

    #pragma unroll
    for (int i = 0; i < 32; ++i)
        sA[i * 260 + t] = emb[(bx * 32 + i) * 256 + t];
    __syncthreads();

    int arow = lane & 15, ak0 = (lane >> 4) << 3;
    short8 af[2][8];
    #pragma unroll
    for (int r = 0; r < 2; ++r)
        #pragma unroll
        for (int s = 0; s < 8; ++s){
            const float* p = &sA[(r * 16 + arow) * 260 + s * 32 + ak0];
            #pragma unroll
            for (int j = 0; j < 8; ++j) af[r][s][j] = (short)f2bf(p[j]);
        }

    const short8* B8 = (const short8*)Bp;
    float4v acc[2][4];
    #pragma unroll
    for (int r = 0; r < 2; ++r)
        #pragma unroll
        for (int c = 0; c < 4; ++c) acc[r][c] = (float4v){0.f, 0.f, 0.f, 0.f};
    #pragma unroll
    for (int s = 0; s < 8; ++s){
        short8 bfr[4];
        #pragma unroll
        for (int c = 0; c < 4; ++c)
            bfr[c] = B8[((by * 16 + w * 4 + c) * 8 + s) * 64 + lane];
        #pragma unroll
        for (int r = 0; r < 2; ++r)
            #pragma unroll
            for (int c = 0; c < 4; ++c)
                acc[r][c] = __builtin_amdgcn_mfma_f32_16x16x32_bf16(af[r][s], bfr[c], acc[r][c], 0, 0, 0);
    }
    int q = lane >> 4, col = lane & 15;
    #pragma unroll
    for (int c = 0; c < 4; ++c){
        int o = (w * 4 + c) * 16 + col;
        float bo = bias[by * 256 + o];
        #pragma unroll
        for (int r = 0; r < 2; ++r)
            #pragma unroll
            for (int rr = 0; rr < 4; ++rr){
                int node = bx * 32 + r * 16 + q * 4 + rr;
                float val = acc[r][c][rr] + bo;
                if (by == 0)      qf[node * 256 + o] = val;
                else if (by == 1) kb[node * 256 + o] = f2bf(val);
                else              vb[node * 256 + o] = f2bf(val);
            }
    }
}

// 32-dim bf16 dot against fp32 q fragments
__device__ __forceinline__ float dot32(const float4* qa, uint4 a, uint4 b, uint4 c, uint4 d){
    float s;
    s  = qa[0].x*blo(a.x) + qa[0].y*bhi(a.x) + qa[0].z*blo(a.y) + qa[0].w*bhi(a.y);
    s += qa[1].x*blo(a.z) + qa[1].y*bhi(a.z) + qa[1].z*blo(a.w) + qa[1].w*bhi(a.w);
    s += qa[2].x*blo(b.x) + qa[2].y*bhi(b.x) + qa[2].z*blo(b.y) + qa[2].w*bhi(b.y);
    s += qa[3].x*blo(b.z) + qa[3].y*bhi(b.z) + qa[3].z*blo(b.w) + qa[3].w*bhi(b.w);
    s += qa[4].x*blo(c.x) + qa[4].y*bhi(c.x) + qa[4].z*blo(c.y) + qa[4].w*bhi(c.y);
    s += qa[5].x*blo(c.z) + qa[5].y*bhi(c.z) + qa[5].z*blo(c.w) + qa[5].w*bhi(c.w);
    s += qa[6].x*blo(d.x) + qa[6].y*bhi(d.x) + qa[6].z*blo(d.y) + qa[6].w*bhi(d.y);
    s += qa[7].x*blo(d.z) + qa[7].y*bhi(d.z) + qa[7].z*blo(d.w) + qa[7].w*bhi(d.w);
    return s;
}

// ---------------- K3: fused attention + tail. 512 threads = 8 waves x 1 node = 8-node tile ----
// (512,4): VGPR cap 128 = exactly 4 waves/SIMD -> 16 waves/CU; score phase 4-way unroll (~115 regs).
__global__ void __launch_bounds__(512, 4) k_attn_tail(
        const float* __restrict__ qf, const unsigned short* __restrict__ kb,
        const unsigned short* __restrict__ vb, const unsigned* __restrict__ adj,
        const float* __restrict__ emb,
        const unsigned short* __restrict__ Bow, const float* __restrict__ ob,
        const unsigned short* __restrict__ Blw, const float* __restrict__ lb,
        const float* __restrict__ g, const float* __restrict__ beta,
        float* __restrict__ out){
    __shared__ float  sS[8][8][SP];      // 33.8 KB scores; later reused as xs[16*264]
    __shared__ int    sNbr[8][MAXD];     // 4 KB
    __shared__ short8 sPk[512];          // 8 KB fragment staging (16 rows; rows 8-15 dead)
    __shared__ float  sInv[8][8];
    __shared__ int    sDeg[8];
    int bx = blockIdx.x, t = threadIdx.x;
    int wv = t >> 6, lane = t & 63;
    int n0 = bx * 8;
    int n = n0 + wv;
    float* xs = (float*)sS;

    // --- Q prefetch (independent of extraction; hides L2 latency behind popc/prefix work) ---
    int h = lane & 7;
    float4 qa[8];
    {
        const float4* q4 = (const float4*)(qf + n * 256 + h * 32);
        #pragma unroll
        for (int i = 0; i < 8; ++i) qa[i] = q4[i];
    }

    // ======== ATTENTION: one node per wave, no barriers ========
    uint2 aw = ((const uint2*)(adj + n * 128))[lane];
    int cnt = __popc(aw.x) + __popc(aw.y);
    int pre = cnt;
    #pragma unroll
    for (int off = 1; off < 64; off <<= 1){
        int tmp = __shfl_up(pre, off);
        if (lane >= off) pre += tmp;
    }
    int tot = __shfl(pre, 63);
    int dg = (tot < MAXD) ? tot : MAXD;
    if (lane == 63) sDeg[wv] = dg;
    int base = pre - cnt;
    int mb = lane * 64;
    unsigned b0 = aw.x, b1 = aw.y;
    while (b0){ int b = __ffs(b0) - 1; b0 &= b0 - 1u; if (base < MAXD) sNbr[wv][base] = mb + b; base++; }
    mb += 32;
    while (b1){ int b = __ffs(b1) - 1; b1 &= b1 - 1u; if (base < MAXD) sNbr[wv][base] = mb + b; base++; }

    if (dg > 0){
        asm volatile("s_waitcnt lgkmcnt(0)" ::: "memory");

        // --- scores: lane = (js = lane>>3, head h = lane&7); 4-way j unroll, 16 loads in flight ---
        int js = lane >> 3;
        for (int jb = 0; jb < dg; jb += 32){
            int j0 = jb + js, j1 = jb + 8 + js, j2 = jb + 16 + js, j3 = jb + 24 + js;
            bool v0 = j0 < dg, v1 = j1 < dg, v2 = j2 < dg, v3 = j3 < dg;
            int m0 = v0 ? sNbr[wv][j0] : sNbr[wv][0];
            int m1 = v1 ? sNbr[wv][j1] : sNbr[wv][0];
            int m2 = v2 ? sNbr[wv][j2] : sNbr[wv][0];
            int m3 = v3 ? sNbr[wv][j3] : sNbr[wv][0];
            const uint4* kr0 = (const uint4*)(kb + m0 * 256) + h * 4;
            const uint4* kr1 = (const uint4*)(kb + m1 * 256) + h * 4;
            const uint4* kr2 = (const uint4*)(kb + m2 * 256) + h * 4;
            const uint4* kr3 = (const uint4*)(kb + m3 * 256) + h * 4;
            uint4 a0 = kr0[0], a1 = kr0[1], a2 = kr0[2], a3 = kr0[3];
            uint4 b0_ = kr1[0], b1_ = kr1[1], b2_ = kr1[2], b3_ = kr1[3];
            uint4 c0 = kr2[0], c1 = kr2[1], c2 = kr2[2], c3 = kr2[3];
            uint4 d0_ = kr3[0], d1_ = kr3[1], d2_ = kr3[2], d3_ = kr3[3];
            float s0 = dot32(qa, a0, a1, a2, a3) * 0.17677669529663687f;
            float s1 = dot32(qa, b0_, b1_, b2_, b3_) * 0.17677669529663687f;
            float s2 = dot32(qa, c0, c1, c2, c3) * 0.17677669529663687f;
            float s3 = dot32(qa, d0_, d1_, d2_, d3_) * 0.17677669529663687f;
            if (v0) sS[wv][h][j0] = s0;
            if (v1) sS[wv][h][j1] = s1;
            if (v2) sS[wv][h][j2] = s2;
            if (v3) sS[wv][h][j3] = s3;
        }
        asm volatile("s_waitcnt lgkmcnt(0)" ::: "memory");

        // --- softmax: lane = (h2 = lane>>3, i2 = lane&7) ---
        int h2 = lane >> 3, i2 = lane & 7;
        float m1 = -1e30f;
        for (int j = i2; j < dg; j += 8) m1 = fmaxf(m1, sS[wv][h2][j]);
        m1 = fmaxf(m1, __shfl_xor(m1, 1));
        m1 = fmaxf(m1, __shfl_xor(m1, 2));
        m1 = fmaxf(m1, __shfl_xor(m1, 4));
        float sum = 0.f;
        for (int j = i2; j < dg; j += 8){ float e = __expf(sS[wv][h2][j] - m1); sS[wv][h2][j] = e; sum += e; }
        sum += __shfl_xor(sum, 1);
        sum += __shfl_xor(sum, 2);
        sum += __shfl_xor(sum, 4);
        if (i2 == 0) sInv[wv][h2] = 1.0f / sum;
        asm volatile("s_waitcnt lgkmcnt(0)" ::: "memory");

        // --- values: lane covers dims 4*lane..4*lane+3; 8-way j unroll; 8B loads (R9 form) ---
        int h3 = lane >> 3;
        const uint2* vb2 = (const uint2*)vb;
        float4 O = {0.f, 0.f, 0.f, 0.f};
        int j = 0;
        for (; j + 8 <= dg; j += 8){
            uint2 uu[8]; float ww[8];
            #pragma unroll
            for (int k = 0; k < 8; ++k){
                uu[k] = vb2[sNbr[wv][j + k] * 64 + lane];
                ww[k] = sS[wv][h3][j + k];
            }
            #pragma unroll
            for (int k = 0; k < 8; ++k){
                O.x += ww[k] * blo(uu[k].x); O.y += ww[k] * bhi(uu[k].x);
                O.z += ww[k] * blo(uu[k].y); O.w += ww[k] * bhi(uu[k].y);
            }
        }
        for (; j < dg; ++j){
            uint2 u = vb2[sNbr[wv][j] * 64 + lane];
            float wgt = sS[wv][h3][j];
            O.x += wgt * blo(u.x); O.y += wgt * bhi(u.x);
            O.z += wgt * blo(u.y); O.w += wgt * bhi(u.y);
        }
        float inv = sInv[wv][h3];

        // --- pack ctx row wv into LDS A-fragments ---
        int d0 = lane * 4;
        int s  = d0 >> 5;
        int l2 = ((d0 >> 3) & 3) * 16 + wv;
        uint2 pk;
        pk.x = (unsigned)f2bf(O.x * inv) | ((unsigned)f2bf(O.y * inv) << 16);
        pk.y = (unsigned)f2bf(O.z * inv) | ((unsigned)f2bf(O.w * inv) << 16);
        ((uint2*)sPk)[(s * 64 + l2) * 2 + ((d0 & 7) >> 2)] = pk;
    }
    __syncthreads();

    // ======== TAIL: out-proj + passthrough -> pack -> lin -> LayerNorm -> GELU ========
    const short8* B8 = (const short8*)Bow;
    float4v acc[2];
    #pragma unroll
    for (int c = 0; c < 2; ++c) acc[c] = (float4v){0.f, 0.f, 0.f, 0.f};
    #pragma unroll
    for (int s = 0; s < 8; ++s){
        short8 a = sPk[s * 64 + lane];
        #pragma unroll
        for (int c = 0; c < 2; ++c)
            acc[c] = __builtin_amdgcn_mfma_f32_16x16x32_bf16(a, B8[((wv * 2 + c) * 8 + s) * 64 + lane], acc[c], 0, 0, 0);
    }
    int q = lane >> 4, col = lane & 15;
    #pragma unroll
    for (int c = 0; c < 2; ++c){
        int o = (wv * 2 + c) * 16 + col;
        float bo = ob[o];
        #pragma unroll
        for (int r = 0; r < 4; ++r){
            int row = q * 4 + r;                 // 0..15; only 0..7 valid
            if (row < 8){
                float x = acc[c][r] + bo;
                if (sDeg[row] == 0) x = emb[(n0 + row) * 256 + o];
                xs[row * 264 + o] = x;
            }
        }
    }
    __syncthreads();

    // pack x -> bf16 fragments (512 entries; rows 8-15 zeroed)
    {
        int l2 = t & 63, s = t >> 6;
        int mm = l2 & 15, k0 = s * 32 + ((l2 >> 4) << 3);
        short8 v;
        if (mm < 8){
            #pragma unroll
            for (int j = 0; j < 8; ++j) v[j] = (short)f2bf(xs[mm * 264 + k0 + j]);
        } else {
            #pragma unroll
            for (int j = 0; j < 8; ++j) v[j] = 0;
        }
        sPk[t] = v;
    }
    __syncthreads();

    // lin MFMA
    const short8* B2 = (const short8*)Blw;
    float4v acc2[2];
    #pragma unroll
    for (int c = 0; c < 2; ++c) acc2[c] = (float4v){0.f, 0.f, 0.f, 0.f};
    #pragma unroll
    for (int s = 0; s < 8; ++s){
        short8 a = sPk[s * 64 + lane];
        #pragma unroll
        for (int c = 0; c < 2; ++c)
            acc2[c] = __builtin_amdgcn_mfma_f32_16x16x32_bf16(a, B2[((wv * 2 + c) * 8 + s) * 64 + lane], acc2[c], 0, 0, 0);
    }
    __syncthreads();                     // pack's xs reads done; reuse xs as ys
    #pragma unroll
    for (int c = 0; c < 2; ++c){
        int o = (wv * 2 + c) * 16 + col;
        float bo = lb[o];
        #pragma unroll
        for (int r = 0; r < 4; ++r){
            int row = q * 4 + r;
            if (row < 8) xs[row * 264 + o] = acc2[c][r] + bo;
        }
    }
    __syncthreads();

    // LayerNorm + exact GELU: waves 0-7, one row each; 64 lanes x 4 cols
    {
        int i = lane;
        float s1 = 0.f, s2 = 0.f;
        #pragma unroll
        for (int jj = 0; jj < 4; ++jj){ float v = xs[wv * 264 + i + 64 * jj]; s1 += v; s2 += v * v; }
        #pragma unroll
        for (int off = 32; off > 0; off >>= 1){ s1 += __shfl_xor(s1, off); s2 += __shfl_xor(s2, off); }
        float mu = s1 * (1.0f / 256.0f);
        float var = s2 * (1.0f / 256.0f) - mu * mu;
        float rs = rsqrtf(fmaxf(var, 0.f) + 1e-5f);
        int nbase = (n0 + wv) * 256;
        #pragma unroll
        for (int jj = 0; jj < 4; ++jj){
            int cc = i + 64 * jj;
            float z = (xs[wv * 264 + cc] - mu) * rs * g[cc] + beta[cc];
            out[nbase + cc] = 0.5f * z * (1.0f + erff(z * 0.70710678118654752f));
        }
    }
}

extern "C" void kernel_launch(void* const* d_in, const int* in_sizes, int n_in,
                              void* d_out, int out_size, void* d_ws, size_t ws_size,
                              hipStream_t stream){
    const float* emb = (const float*)d_in[0];
    const int*   ei  = (const int*)d_in[1];
    const float* ipw = (const float*)d_in[2];
    const float* ipb = (const float*)d_in[3];
    const float* ow  = (const float*)d_in[4];
    const float* ob  = (const float*)d_in[5];
    const float* lw  = (const float*)d_in[6];
    const float* lb  = (const float*)d_in[7];
    const float* g   = (const float*)d_in[8];
    const float* bet = (const float*)d_in[9];

    char* ws = (char*)d_ws;
    unsigned*       adj  = (unsigned*)(ws);                    // 2 MiB
    unsigned short* bipw = (unsigned short*)(ws + 2113536);    // 384 KiB
    unsigned short* bow  = (unsigned short*)(ws + 2506752);    // 128 KiB
    unsigned short* blw  = (unsigned short*)(ws + 2637824);    // 128 KiB
    float*          qf   = (float*)(ws + 2768896);             // 4 MiB
    unsigned short* kb   = (unsigned short*)(ws + 6963200);    // 2 MiB
    unsigned short* vb   = (unsigned short*)(ws + 9060352);    // 2 MiB

    k_packw    <<<160, 256, 0, stream>>>(ipw, ow, lw, bipw, bow, blw, adj);
    k_gqkv     <<<dim3(128, 3), 256, 0, stream>>>(emb, bipw, ipb, qf, kb, vb, ei, adj);
    k_attn_tail<<<512, 512, 0, stream>>>(qf, kb, vb, adj, emb, bow, ob, blw, lb, g, bet, (float*)d_out);
}

// Round 14
// 125.708 us; speedup vs baseline: 1.0717x; 1.0717x over previous
//
#include <hip/hip_runtime.h>
#include <math.h>

#define NN 4096
#define DD 256
#define EE 131072
#define MAXD 128
#define SP 132          // sS row stride; 132%32==4 -> conflict-free

typedef __attribute__((ext_vector_type(8))) short short8;
typedef __attribute__((ext_vector_type(4))) float float4v;

__device__ __forceinline__ unsigned short f2bf(float f){
    unsigned u = __float_as_uint(f);
    return (unsigned short)((u + 0x7fffu + ((u >> 16) & 1u)) >> 16);   // RNE
}
__device__ __forceinline__ float blo(unsigned u){ return __uint_as_float(u << 16); }
__device__ __forceinline__ float bhi(unsigned u){ return __uint_as_float(u & 0xffff0000u); }

// ---------------- K1: pack weights to MFMA fragments + zero adj ----------------
__device__ __forceinline__ void pack_one(const float* __restrict__ src, unsigned short* __restrict__ dst, int e){
    int lane = e & 63;
    int row = ((e >> 9) << 4) + (lane & 15);
    int k0 = ((e >> 6) & 7) * 32 + ((lane >> 4) << 3);
    const float* p = src + row * DD + k0;
    short8 v;
    #pragma unroll
    for (int j = 0; j < 8; ++j) v[j] = (short)f2bf(p[j]);
    ((short8*)dst)[e] = v;
}

__global__ void k_packw(const float* __restrict__ ipw, const float* __restrict__ ow, const float* __restrict__ lw,
                        unsigned short* __restrict__ bipw, unsigned short* __restrict__ bow,
                        unsigned short* __restrict__ blw, unsigned* __restrict__ adj){
    int e = blockIdx.x * 256 + threadIdx.x;       // 40960 threads
    for (int i = e; i < 524288; i += 40960) adj[i] = 0u;   // zero 2MB adj
    if (e < 24576)       pack_one(ipw, bipw, e);
    else if (e < 32768)  pack_one(ow,  bow,  e - 24576);
    else                 pack_one(lw,  blw,  e - 32768);
}

// ---------------- K2: QKV GEMM (Q fp32, K/V bf16) + fused edge scatter ----------------
__global__ void __launch_bounds__(256) k_gqkv(const float* __restrict__ emb, const unsigned short* __restrict__ Bp,
                                              const float* __restrict__ bias, float* __restrict__ qf,
                                              unsigned short* __restrict__ kb, unsigned short* __restrict__ vb,
                                              const int* __restrict__ ei, unsigned* __restrict__ adj){
    __shared__ float sA[16 * 260];
    int bx = blockIdx.x, by = blockIdx.y;
    int t = threadIdx.x, w = t >> 6, lane = t & 63;

    // fire-and-forget edge scatter (adj zeroed by k_packw)
    int gid = (by * gridDim.x + bx) * 256 + t;
    if (gid < EE){
        int s = ei[gid], d = ei[EE + gid];
        if (s != d){
            atomicOr(&adj[s * 128 + (d >> 5)], 1u << (d & 31));
            atomicOr(&adj[d * 128 + (s >> 5)], 1u << (s & 31));
        }
    }

    #pragma unroll
    for (int i = 0; i < 16; ++i)
        sA[i * 260 + t] = emb[(bx * 16 + i) * 256 + t];
    __syncthreads();

    int arow = lane & 15, ak0 = (lane >> 4) << 3;
    short8 af[8];
    #pragma unroll
    for (int s = 0; s < 8; ++s){
        const float* p = &sA[arow * 260 + s * 32 + ak0];
        #pragma unroll
        for (int j = 0; j < 8; ++j) af[s][j] = (short)f2bf(p[j]);
    }

    const short8* B8 = (const short8*)Bp;
    float4v acc[4];
    #pragma unroll
    for (int c = 0; c < 4; ++c) acc[c] = (float4v){0.f, 0.f, 0.f, 0.f};
    #pragma unroll
    for (int s = 0; s < 8; ++s){
        #pragma unroll
        for (int c = 0; c < 4; ++c){
            int to = by * 16 + w * 4 + c;
            acc[c] = __builtin_amdgcn_mfma_f32_16x16x32_bf16(af[s], B8[(to * 8 + s) * 64 + lane], acc[c], 0, 0, 0);
        }
    }
    int q = lane >> 4, col = lane & 15;
    #pragma unroll
    for (int c = 0; c < 4; ++c){
        int o = (w * 4 + c) * 16 + col;
        float bo = bias[by * 256 + o];
        #pragma unroll
        for (int r = 0; r < 4; ++r){
            int node = bx * 16 + q * 4 + r;
            float val = acc[c][r] + bo;
            if (by == 0)      qf[node * 256 + o] = val;
            else if (by == 1) kb[node * 256 + o] = f2bf(val);
            else              vb[node * 256 + o] = f2bf(val);
        }
    }
}

// 32-dim bf16 dot against fp32 q fragments
__device__ __forceinline__ float dot32(const float4* qa, uint4 a, uint4 b, uint4 c, uint4 d){
    float s;
    s  = qa[0].x*blo(a.x) + qa[0].y*bhi(a.x) + qa[0].z*blo(a.y) + qa[0].w*bhi(a.y);
    s += qa[1].x*blo(a.z) + qa[1].y*bhi(a.z) + qa[1].z*blo(a.w) + qa[1].w*bhi(a.w);
    s += qa[2].x*blo(b.x) + qa[2].y*bhi(b.x) + qa[2].z*blo(b.y) + qa[2].w*bhi(b.y);
    s += qa[3].x*blo(b.z) + qa[3].y*bhi(b.z) + qa[3].z*blo(b.w) + qa[3].w*bhi(b.w);
    s += qa[4].x*blo(c.x) + qa[4].y*bhi(c.x) + qa[4].z*blo(c.y) + qa[4].w*bhi(c.y);
    s += qa[5].x*blo(c.z) + qa[5].y*bhi(c.z) + qa[5].z*blo(c.w) + qa[5].w*bhi(c.w);
    s += qa[6].x*blo(d.x) + qa[6].y*bhi(d.x) + qa[6].z*blo(d.y) + qa[6].w*bhi(d.y);
    s += qa[7].x*blo(d.z) + qa[7].y*bhi(d.z) + qa[7].z*blo(d.w) + qa[7].w*bhi(d.w);
    return s;
}

// ---------------- K3: fused attention + tail. 512 threads = 8 waves x 1 node = 8-node tile ----
// R9 structure (measured best 125.1 us): uncapped VGPRs, 16 waves/CU, no min-waves clause.
__global__ void __launch_bounds__(512) k_attn_tail(
        const float* __restrict__ qf, const unsigned short* __restrict__ kb,
        const unsigned short* __restrict__ vb, const unsigned* __restrict__ adj,
        const float* __restrict__ emb,
        const unsigned short* __restrict__ Bow, const float* __restrict__ ob,
        const unsigned short* __restrict__ Blw, const float* __restrict__ lb,
        const float* __restrict__ g, const float* __restrict__ beta,
        float* __restrict__ out){
    __shared__ float  sS[8][8][SP];      // 33.8 KB scores; later reused as xs[16*264]
    __shared__ int    sNbr[8][MAXD];     // 4 KB
    __shared__ short8 sPk[512];          // 8 KB fragment staging (16 rows; rows 8-15 dead)
    __shared__ float  sInv[8][8];
    __shared__ int    sDeg[8];
    int bx = blockIdx.x, t = threadIdx.x;
    int wv = t >> 6, lane = t & 63;
    int n0 = bx * 8;
    int n = n0 + wv;                     // this wave's node; row within tile = wv
    float* xs = (float*)sS;

    // ======== ATTENTION: one node per wave, no barriers ========
    uint2 aw = ((const uint2*)(adj + n * 128))[lane];
    int cnt = __popc(aw.x) + __popc(aw.y);
    int pre = cnt;
    #pragma unroll
    for (int off = 1; off < 64; off <<= 1){
        int tmp = __shfl_up(pre, off);
        if (lane >= off) pre += tmp;
    }
    int tot = __shfl(pre, 63);
    int dg = (tot < MAXD) ? tot : MAXD;
    if (lane == 63) sDeg[wv] = dg;
    int base = pre - cnt;
    int mb = lane * 64;
    unsigned b0 = aw.x, b1 = aw.y;
    while (b0){ int b = __ffs(b0) - 1; b0 &= b0 - 1u; if (base < MAXD) sNbr[wv][base] = mb + b; base++; }
    mb += 32;
    while (b1){ int b = __ffs(b1) - 1; b1 &= b1 - 1u; if (base < MAXD) sNbr[wv][base] = mb + b; base++; }

    if (dg > 0){
        asm volatile("s_waitcnt lgkmcnt(0)" ::: "memory");

        // --- scores: lane = (js = lane>>3, head h = lane&7); 2-way j unroll ---
        int js = lane >> 3, h = lane & 7;
        float4 qa[8];
        const float4* q4 = (const float4*)(qf + n * 256 + h * 32);
        #pragma unroll
        for (int i = 0; i < 8; ++i) qa[i] = q4[i];
        for (int jb = 0; jb < dg; jb += 16){
            int j0 = jb + js, j1 = jb + 8 + js;
            bool v0 = j0 < dg, v1 = j1 < dg;
            int m0 = v0 ? sNbr[wv][j0] : sNbr[wv][0];
            int m1 = v1 ? sNbr[wv][j1] : sNbr[wv][0];
            const uint4* kr0 = (const uint4*)(kb + m0 * 256) + h * 4;
            const uint4* kr1 = (const uint4*)(kb + m1 * 256) + h * 4;
            uint4 a0 = kr0[0], a1 = kr0[1], a2 = kr0[2], a3 = kr0[3];
            uint4 c0 = kr1[0], c1 = kr1[1], c2 = kr1[2], c3 = kr1[3];
            float s0 = dot32(qa, a0, a1, a2, a3) * 0.17677669529663687f;
            float s1 = dot32(qa, c0, c1, c2, c3) * 0.17677669529663687f;
            if (v0) sS[wv][h][j0] = s0;
            if (v1) sS[wv][h][j1] = s1;
        }
        asm volatile("s_waitcnt lgkmcnt(0)" ::: "memory");

        // --- softmax: lane = (h2 = lane>>3, i2 = lane&7) ---
        int h2 = lane >> 3, i2 = lane & 7;
        float m1 = -1e30f;
        for (int j = i2; j < dg; j += 8) m1 = fmaxf(m1, sS[wv][h2][j]);
        m1 = fmaxf(m1, __shfl_xor(m1, 1));
        m1 = fmaxf(m1, __shfl_xor(m1, 2));
        m1 = fmaxf(m1, __shfl_xor(m1, 4));
        float sum = 0.f;
        for (int j = i2; j < dg; j += 8){ float e = __expf(sS[wv][h2][j] - m1); sS[wv][h2][j] = e; sum += e; }
        sum += __shfl_xor(sum, 1);
        sum += __shfl_xor(sum, 2);
        sum += __shfl_xor(sum, 4);
        if (i2 == 0) sInv[wv][h2] = 1.0f / sum;
        asm volatile("s_waitcnt lgkmcnt(0)" ::: "memory");

        // --- values: lane covers dims 4*lane..4*lane+3; 8-way j unroll; 8B loads ---
        int h3 = lane >> 3;
        const uint2* vb2 = (const uint2*)vb;
        float4 O = {0.f, 0.f, 0.f, 0.f};
        int j = 0;
        for (; j + 8 <= dg; j += 8){
            uint2 uu[8]; float ww[8];
            #pragma unroll
            for (int k = 0; k < 8; ++k){
                uu[k] = vb2[sNbr[wv][j + k] * 64 + lane];
                ww[k] = sS[wv][h3][j + k];
            }
            #pragma unroll
            for (int k = 0; k < 8; ++k){
                O.x += ww[k] * blo(uu[k].x); O.y += ww[k] * bhi(uu[k].x);
                O.z += ww[k] * blo(uu[k].y); O.w += ww[k] * bhi(uu[k].y);
            }
        }
        for (; j < dg; ++j){
            uint2 u = vb2[sNbr[wv][j] * 64 + lane];
            float wgt = sS[wv][h3][j];
            O.x += wgt * blo(u.x); O.y += wgt * bhi(u.x);
            O.z += wgt * blo(u.y); O.w += wgt * bhi(u.y);
        }
        float inv = sInv[wv][h3];

        // --- pack ctx row wv into LDS A-fragments ---
        int d0 = lane * 4;
        int s  = d0 >> 5;
        int l2 = ((d0 >> 3) & 3) * 16 + wv;
        uint2 pk;
        pk.x = (unsigned)f2bf(O.x * inv) | ((unsigned)f2bf(O.y * inv) << 16);
        pk.y = (unsigned)f2bf(O.z * inv) | ((unsigned)f2bf(O.w * inv) << 16);
        ((uint2*)sPk)[(s * 64 + l2) * 2 + ((d0 & 7) >> 2)] = pk;
    }
    __syncthreads();

    // ======== TAIL: out-proj + passthrough -> pack -> lin -> LayerNorm -> GELU ========
    const short8* B8 = (const short8*)Bow;
    float4v acc[2];
    #pragma unroll
    for (int c = 0; c < 2; ++c) acc[c] = (float4v){0.f, 0.f, 0.f, 0.f};
    #pragma unroll
    for (int s = 0; s < 8; ++s){
        short8 a = sPk[s * 64 + lane];
        #pragma unroll
        for (int c = 0; c < 2; ++c)
            acc[c] = __builtin_amdgcn_mfma_f32_16x16x32_bf16(a, B8[((wv * 2 + c) * 8 + s) * 64 + lane], acc[c], 0, 0, 0);
    }
    int q = lane >> 4, col = lane & 15;
    #pragma unroll
    for (int c = 0; c < 2; ++c){
        int o = (wv * 2 + c) * 16 + col;
        float bo = ob[o];
        #pragma unroll
        for (int r = 0; r < 4; ++r){
            int row = q * 4 + r;                 // 0..15; only 0..7 valid
            if (row < 8){
                float x = acc[c][r] + bo;
                if (sDeg[row] == 0) x = emb[(n0 + row) * 256 + o];
                xs[row * 264 + o] = x;
            }
        }
    }
    __syncthreads();

    // pack x -> bf16 fragments (512 entries; rows 8-15 zeroed)
    {
        int l2 = t & 63, s = t >> 6;
        int mm = l2 & 15, k0 = s * 32 + ((l2 >> 4) << 3);
        short8 v;
        if (mm < 8){
            #pragma unroll
            for (int j = 0; j < 8; ++j) v[j] = (short)f2bf(xs[mm * 264 + k0 + j]);
        } else {
            #pragma unroll
            for (int j = 0; j < 8; ++j) v[j] = 0;
        }
        sPk[t] = v;
    }
    __syncthreads();

    // lin MFMA
    const short8* B2 = (const short8*)Blw;
    float4v acc2[2];
    #pragma unroll
    for (int c = 0; c < 2; ++c) acc2[c] = (float4v){0.f, 0.f, 0.f, 0.f};
    #pragma unroll
    for (int s = 0; s < 8; ++s){
        short8 a = sPk[s * 64 + lane];
        #pragma unroll
        for (int c = 0; c < 2; ++c)
            acc2[c] = __builtin_amdgcn_mfma_f32_16x16x32_bf16(a, B2[((wv * 2 + c) * 8 + s) * 64 + lane], acc2[c], 0, 0, 0);
    }
    __syncthreads();                     // pack's xs reads done; reuse xs as ys
    #pragma unroll
    for (int c = 0; c < 2; ++c){
        int o = (wv * 2 + c) * 16 + col;
        float bo = lb[o];
        #pragma unroll
        for (int r = 0; r < 4; ++r){
            int row = q * 4 + r;
            if (row < 8) xs[row * 264 + o] = acc2[c][r] + bo;
        }
    }
    __syncthreads();

    // LayerNorm + exact GELU: waves 0-7, one row each; 64 lanes x 4 cols
    {
        int i = lane;
        float s1 = 0.f, s2 = 0.f;
        #pragma unroll
        for (int jj = 0; jj < 4; ++jj){ float v = xs[wv * 264 + i + 64 * jj]; s1 += v; s2 += v * v; }
        #pragma unroll
        for (int off = 32; off > 0; off >>= 1){ s1 += __shfl_xor(s1, off); s2 += __shfl_xor(s2, off); }
        float mu = s1 * (1.0f / 256.0f);
        float var = s2 * (1.0f / 256.0f) - mu * mu;
        float rs = rsqrtf(fmaxf(var, 0.f) + 1e-5f);
        int nbase = (n0 + wv) * 256;
        #pragma unroll
        for (int jj = 0; jj < 4; ++jj){
            int cc = i + 64 * jj;
            float z = (xs[wv * 264 + cc] - mu) * rs * g[cc] + beta[cc];
            out[nbase + cc] = 0.5f * z * (1.0f + erff(z * 0.70710678118654752f));
        }
    }
}

extern "C" void kernel_launch(void* const* d_in, const int* in_sizes, int n_in,
                              void* d_out, int out_size, void* d_ws, size_t ws_size,
                              hipStream_t stream){
    const float* emb = (const float*)d_in[0];
    const int*   ei  = (const int*)d_in[1];
    const float* ipw = (const float*)d_in[2];
    const float* ipb = (const float*)d_in[3];
    const float* ow  = (const float*)d_in[4];
    const float* ob  = (const float*)d_in[5];
    const float* lw  = (const float*)d_in[6];
    const float* lb  = (const float*)d_in[7];
    const float* g   = (const float*)d_in[8];
    const float* bet = (const float*)d_in[9];

    char* ws = (char*)d_ws;
    unsigned*       adj  = (unsigned*)(ws);                    // 2 MiB
    unsigned short* bipw = (unsigned short*)(ws + 2113536);    // 384 KiB
    unsigned short* bow  = (unsigned short*)(ws + 2506752);    // 128 KiB
    unsigned short* blw  = (unsigned short*)(ws + 2637824);    // 128 KiB
    float*          qf   = (float*)(ws + 2768896);             // 4 MiB
    unsigned short* kb   = (unsigned short*)(ws + 6963200);    // 2 MiB
    unsigned short* vb   = (unsigned short*)(ws + 9060352);    // 2 MiB

    k_packw    <<<160, 256, 0, stream>>>(ipw, ow, lw, bipw, bow, blw, adj);
    k_gqkv     <<<dim3(256, 3), 256, 0, stream>>>(emb, bipw, ipb, qf, kb, vb, ei, adj);
    k_attn_tail<<<512, 512, 0, stream>>>(qf, kb, vb, adj, emb, bow, ob, blw, lb, g, bet, (float*)d_out);
}